// Round 14
// baseline (285.946 us; speedup 1.0000x reference)
//
#include <hip/hip_runtime.h>
#include <hip/hip_bf16.h>
#include <hip/hip_fp16.h>
#include <hip/hip_fp8.h>

#define NN 100000        // nodes
#define NE 3200000       // edges
#define FF 32            // node features
#define LL 50            // node labels
#define ELB 10           // edge labels
#define KK 16            // out dim
#define NWIDX (LL * LL * ELB)   // 25000 distinct weight indices

#define CH 8192          // edges per p1 block (long runs -> low write amplification)
#define NBLK_P1 391      // ceil(NE/CH)
#define NBUK 391         // ceil(NN/256) buckets of 256 nodes
#define CAP 9216         // slots per bucket (mean 8192, sigma ~90 -> +11 sigma)

typedef float floatx2 __attribute__((ext_vector_type(2)));

__device__ __forceinline__ float fast_tanh(float x) {
    float e = __expf(2.0f * x);
    return 1.0f - 2.0f / (e + 1.0f);   // saturates correctly at +/-1
}

// ---------- phase 1: x->fp8 convert + Wi interleave (fp16) + labels8 + LDS counting-sort ----------
// rec u32 = src(17b)<<12 | elab(4b)<<8 | dst_local(8b)
__global__ __launch_bounds__(512) void p1_scatter(const int* __restrict__ esrc,
                                                  const int* __restrict__ edst,
                                                  const int* __restrict__ elab,
                                                  const float* __restrict__ x,
                                                  const float* __restrict__ W1,
                                                  const float* __restrict__ W2,
                                                  const float* __restrict__ W3,
                                                  ushort4* __restrict__ Wi,
                                                  unsigned char* __restrict__ labels8,
                                                  const int* __restrict__ labels,
                                                  unsigned* __restrict__ xb,
                                                  int* __restrict__ cursor,
                                                  unsigned* __restrict__ recs) {
    __shared__ int lcnt[NBUK];        // counts, then per-bucket local cursor
    __shared__ int lofs[NBUK];        // local exclusive prefix (sorted slot base)
    __shared__ int lbase[NBUK];       // global reserved base per bucket
    __shared__ int sc[512];           // scan scratch
    __shared__ unsigned srec[CH];     // 32 KB: records at sorted slots
    __shared__ unsigned sgad[CH];     // 32 KB: global dest index per sorted slot
    int tid = threadIdx.x;
    // x -> fp8 (independent work, folded in to save a launch)
    for (int i = blockIdx.x * 512 + tid; i < NN * FF / 4; i += NBLK_P1 * 512) {
        float4 v = ((const float4*)x)[i];
        __hip_fp8_e4m3 a(v.x), b(v.y), c(v.z), d(v.w);
        xb[i] = (unsigned)a.__x | ((unsigned)b.__x << 8) |
                ((unsigned)c.__x << 16) | ((unsigned)d.__x << 24);
    }
    // interleave W1/W2/W3 -> Wi[widx] = fp16 (w1,w2,w3,0): 200 KB table, one gather serves all 3 convs
    for (int i = blockIdx.x * 512 + tid; i < NWIDX; i += NBLK_P1 * 512) {
        ushort4 w;
        w.x = __half_as_ushort(__float2half(W1[i]));
        w.y = __half_as_ushort(__float2half(W2[i]));
        w.z = __half_as_ushort(__float2half(W3[i]));
        w.w = 0;
        Wi[i] = w;
    }
    // labels -> u8 (100 KB table: 4x fewer lines for p2's hot gather)
    for (int i = blockIdx.x * 512 + tid; i < NN; i += NBLK_P1 * 512)
        labels8[i] = (unsigned char)labels[i];
    for (int i = tid; i < NBUK; i += 512) lcnt[i] = 0;
    __syncthreads();
    long e0 = (long)blockIdx.x * CH;
    long rem = NE - e0;
    int cnt = rem < CH ? (int)rem : CH;   // always divisible by 4
    int nq = cnt >> 2;
    const int4* edst4 = (const int4*)(edst + e0);
    const int4* esrc4 = (const int4*)(esrc + e0);
    const int4* elab4 = (const int4*)(elab + e0);
    // pass A: count per bucket
    for (int i = tid; i < nq; i += 512) {
        int4 d = edst4[i];
        atomicAdd(&lcnt[d.x >> 8], 1);
        atomicAdd(&lcnt[d.y >> 8], 1);
        atomicAdd(&lcnt[d.z >> 8], 1);
        atomicAdd(&lcnt[d.w >> 8], 1);
    }
    __syncthreads();
    // local exclusive prefix over buckets (Hillis-Steele on 512-padded array)
    sc[tid] = (tid < NBUK) ? lcnt[tid] : 0;
    __syncthreads();
    for (int ofs = 1; ofs < 512; ofs <<= 1) {
        int t = (tid >= ofs) ? sc[tid - ofs] : 0;
        __syncthreads();
        sc[tid] += t;
        __syncthreads();
    }
    // pass B: reserve contiguous global runs (cursor is relative, zero-init by memset)
    if (tid < NBUK) {
        int c = lcnt[tid];
        lofs[tid] = sc[tid] - c;     // local sorted base
        lbase[tid] = c ? atomicAdd(&cursor[tid], c) : 0;
        lcnt[tid] = 0;               // reuse as local cursor
    }
    __syncthreads();
    // pass C: re-read edge chunk (L2-hot), stage sorted in LDS
    for (int i = tid; i < nq; i += 512) {
        int4 s4 = esrc4[i];
        int4 l4 = elab4[i];
        int4 d4 = edst4[i];
#pragma unroll
        for (int k = 0; k < 4; ++k) {
            int s  = (&s4.x)[k];
            int d  = (&d4.x)[k];
            int el = (&l4.x)[k];
            int b = d >> 8;
            int pos = atomicAdd(&lcnt[b], 1);
            int slot = lofs[b] + pos;
            srec[slot] = ((unsigned)s << 12) | ((unsigned)el << 8) | (unsigned)(d & 255);
            int rel = lbase[b] + pos;
            sgad[slot] = (rel < CAP) ? (unsigned)(b * CAP + rel) : 0xFFFFFFFFu;
        }
    }
    __syncthreads();
    // pass D: coalesced write-out — consecutive sorted slots -> consecutive global addrs
    for (int i = tid; i < cnt; i += 512) {
        unsigned g = sgad[i];
        if (g != 0xFFFFFFFFu)
            recs[g] = srec[i];
    }
}

// ---------- phase 2: per-bucket exact CSR (permutation in LDS) + coalesced per-layer ed write ----------
// edL u32 = w_fp15(15) | src(17)<<15   (one array per conv layer)
__global__ __launch_bounds__(1024) void p2_local(const int* __restrict__ cursor,
                                                 const unsigned* __restrict__ recs,
                                                 const unsigned char* __restrict__ labels8,
                                                 const ushort4* __restrict__ Wi,
                                                 unsigned* __restrict__ ed1,
                                                 unsigned* __restrict__ ed2,
                                                 unsigned* __restrict__ ed3,
                                                 int* __restrict__ gstart,
                                                 int* __restrict__ gcnt) {
    __shared__ int deg[256], loff[256], lcur[256], sc[256];
    __shared__ int labd[256];
    __shared__ unsigned pk32[CAP];    // 36 KB: widx(15)<<17 | src(17) at sorted slot
    int b = blockIdx.x, tid = threadIdx.x;
    int base = b * CAP;
    int n = cursor[b];
    if (n > CAP) n = CAP;
    if (tid < 256) {
        int node = (b << 8) + tid;
        deg[tid] = 0;
        lcur[tid] = 0;
        labd[tid] = (node < NN) ? (int)labels8[node] : 0;
    }
    __syncthreads();
    for (int i = tid; i < n; i += 1024)
        atomicAdd(&deg[(int)(recs[base + i] & 255)], 1);
    __syncthreads();
    if (tid < 256) sc[tid] = deg[tid];
    __syncthreads();
    for (int ofs = 1; ofs < 256; ofs <<= 1) {
        int t = (tid >= ofs && tid < 256) ? sc[tid - ofs] : 0;
        __syncthreads();
        if (tid < 256) sc[tid] += t;
        __syncthreads();
    }
    if (tid < 256) {
        loff[tid] = sc[tid] - deg[tid];   // exclusive
        int node = (b << 8) + tid;
        if (node < NN) { gstart[node] = base + loff[tid]; gcnt[node] = deg[tid]; }
    }
    __syncthreads();
    // place: resolve widx, stash packed u32 at its CSR slot in LDS (no global scatter)
    for (int i = tid; i < n; i += 1024) {
        unsigned r = recs[base + i];
        int dl  = (int)(r & 255);
        int el  = (int)((r >> 8) & 15);
        int src = (int)(r >> 12);
        int widx = (int)labels8[src] * (LL * ELB) + labd[dl] * ELB + el;
        int ofs = atomicAdd(&lcur[dl], 1);
        pk32[loff[dl] + ofs] = ((unsigned)widx << 17) | (unsigned)src;
    }
    __syncthreads();
    // write-out: sequential slots -> three coalesced u32 streams (no write amplification)
    for (int slot = tid; slot < n; slot += 1024) {
        unsigned v = pk32[slot];
        int widx = (int)(v >> 17);
        unsigned sb = (v & 0x1FFFFu) << 15;   // src in bits 15..31
        ushort4 wv = Wi[widx];                // single 8B gather, 200 KB table
        ed1[base + slot] = (unsigned)(wv.x >> 1) | sb;
        ed2[base + slot] = (unsigned)(wv.y >> 1) | sb;
        ed3[base + slot] = (unsigned)(wv.z >> 1) | sb;
    }
}

// ---------- conv-E: half-wave per node, LDS stage + prefetch + dbuf (conv-D proven),
// ----------         4 lanes/row 8B fp8 gathers -> j-loop halved to 4 ----------
__global__ __launch_bounds__(256) void conv_kernel(const unsigned char* __restrict__ xin,
                                                   unsigned char* __restrict__ hout,
                                                   const int* __restrict__ gstart,
                                                   const int* __restrict__ gcnt,
                                                   const unsigned* __restrict__ ed,
                                                   const float* __restrict__ bias,
                                                   const int* __restrict__ labels) {
    __shared__ unsigned stage[2][8][64];   // double-buffered (w_bits, src*32 byte-off)
    int tid = threadIdx.x;
    int hw = tid >> 5, lane = tid & 31;
    int node = (blockIdx.x << 3) + hw;   // grid exact: 12500*8 = 100000
    int s = gstart[node];
    int n = gcnt[node];
    float bb = bias[labels[node]];       // hoisted: latency hides under first tile
    int eb  = lane >> 2;         // edge sub-slot 0..7 within each group of 8
    int fg2 = (lane & 3) << 3;   // feature byte offset 0/8/16/24 (8 feats per lane)
    float acc0 = 0.f, acc1 = 0.f, acc2 = 0.f, acc3 = 0.f;
    float acc4 = 0.f, acc5 = 0.f, acc6 = 0.f, acc7 = 0.f;
    // prefetch tile 0 (clamped addr stays inside this bucket's region; ws mem is valid)
    unsigned e_cur = ed[s + (lane < n ? lane : 0)];
    int buf = 0;
    for (int base = 0; base < n; base += 32) {
        int idx = base + lane;
        float w = 0.f;
        unsigned so = 0u;
        if (idx < n) {
            // decode u32 rec: w_fp15(15) | src(17)<<15
            unsigned short h = (unsigned short)((e_cur & 0x7FFFu) << 1);
            w = __half2float(__ushort_as_half(h));
            so = (e_cur >> 15) << 5;                // src * 32 bytes (fp8 row)
        }
        ((uint2*)&stage[buf][hw][0])[lane] = make_uint2(__float_as_uint(w), so);
        // issue next tile's ed load BEFORE the j-loop: latency hides under the gathers
        int nb = base + 32;
        if (nb < n) {
            int i2 = nb + lane;
            e_cur = ed[s + (i2 < n ? i2 : nb)];
        }
        __builtin_amdgcn_wave_barrier();   // same-wave DS RAW: DS pipe in-order
        // 4 sub-iters x 8 edges: 8B gather covers 8 features -> half the instructions
#pragma unroll
        for (int j = 0; j < 4; ++j) {
            uint2 ws = ((const uint2*)&stage[buf][hw][0])[j * 8 + eb];
            uint2 pv = *(const uint2*)(xin + ws.y + fg2);   // 8 fp8 feats of the row
            floatx2 a0 = __builtin_amdgcn_cvt_pk_f32_fp8((int)pv.x, false);
            floatx2 a1 = __builtin_amdgcn_cvt_pk_f32_fp8((int)pv.x, true);
            floatx2 b0 = __builtin_amdgcn_cvt_pk_f32_fp8((int)pv.y, false);
            floatx2 b1 = __builtin_amdgcn_cvt_pk_f32_fp8((int)pv.y, true);
            float we = __uint_as_float(ws.x);
            acc0 += we * a0.x;  acc1 += we * a0.y;
            acc2 += we * a1.x;  acc3 += we * a1.y;
            acc4 += we * b0.x;  acc5 += we * b0.y;
            acc6 += we * b1.x;  acc7 += we * b1.y;
        }
        buf ^= 1;   // next stage-write targets the other buffer: no trailing barrier
    }
    // reduce across the 8 edge subgroups (lane bits 2,3,4 -> masks 4,8,16; stays in half-wave)
#pragma unroll
    for (int m = 4; m <= 16; m <<= 1) {
        acc0 += __shfl_xor(acc0, m);  acc1 += __shfl_xor(acc1, m);
        acc2 += __shfl_xor(acc2, m);  acc3 += __shfl_xor(acc3, m);
        acc4 += __shfl_xor(acc4, m);  acc5 += __shfl_xor(acc5, m);
        acc6 += __shfl_xor(acc6, m);  acc7 += __shfl_xor(acc7, m);
    }
    if (lane < 4) {
        __hip_fp8_e4m3 q0(fast_tanh(acc0 + bb));
        __hip_fp8_e4m3 q1(fast_tanh(acc1 + bb));
        __hip_fp8_e4m3 q2(fast_tanh(acc2 + bb));
        __hip_fp8_e4m3 q3(fast_tanh(acc3 + bb));
        __hip_fp8_e4m3 q4(fast_tanh(acc4 + bb));
        __hip_fp8_e4m3 q5(fast_tanh(acc5 + bb));
        __hip_fp8_e4m3 q6(fast_tanh(acc6 + bb));
        __hip_fp8_e4m3 q7(fast_tanh(acc7 + bb));
        unsigned lo = (unsigned)q0.__x | ((unsigned)q1.__x << 8) |
                      ((unsigned)q2.__x << 16) | ((unsigned)q3.__x << 24);
        unsigned hi = (unsigned)q4.__x | ((unsigned)q5.__x << 8) |
                      ((unsigned)q6.__x << 16) | ((unsigned)q7.__x << 24);
        ((uint2*)(hout + ((long)node << 5)))[lane] = make_uint2(lo, hi);  // lane==fg2/8
    }
}

// ---------- label pooling: sums[L][F] from fp8 h ----------
__global__ __launch_bounds__(256) void lsum_kernel(const unsigned* __restrict__ h,
                                                   const int* __restrict__ labels,
                                                   float* __restrict__ sums) {
    __shared__ float ls[LL * FF];
    int tid = threadIdx.x;
    for (int i = tid; i < LL * FF; i += 256) ls[i] = 0.f;
    __syncthreads();
    for (int i = blockIdx.x * 256 + tid; i < NN * 8; i += gridDim.x * 256) {
        unsigned pv = h[i];
        int nodei = i >> 3;
        int fb = (i & 7) << 2;
        int l = labels[nodei];
        floatx2 lo = __builtin_amdgcn_cvt_pk_f32_fp8((int)pv, false);
        floatx2 hi = __builtin_amdgcn_cvt_pk_f32_fp8((int)pv, true);
        float* bp = &ls[l * FF + fb];
        atomicAdd(bp + 0, lo.x);
        atomicAdd(bp + 1, lo.y);
        atomicAdd(bp + 2, hi.x);
        atomicAdd(bp + 3, hi.y);
    }
    __syncthreads();
    for (int i = tid; i < LL * FF; i += 256) atomicAdd(&sums[i], ls[i]);
}

// ---------- final resize ----------
__global__ __launch_bounds__(256) void resize_kernel(const float* __restrict__ sums,
                                                     const float* __restrict__ Wr,
                                                     const float* __restrict__ br,
                                                     float* __restrict__ out) {
    __shared__ float red[256][KK];
    int tid = threadIdx.x;
    float acc[KK];
#pragma unroll
    for (int k = 0; k < KK; ++k) acc[k] = 0.f;
    for (int p = tid; p < LL * FF; p += 256) {
        float sv = sums[p];
#pragma unroll
        for (int k = 0; k < KK; ++k) acc[k] += sv * Wr[p * KK + k];
    }
#pragma unroll
    for (int k = 0; k < KK; ++k) red[tid][k] = acc[k];
    __syncthreads();
    for (int sft = 128; sft > 0; sft >>= 1) {
        if (tid < sft) {
#pragma unroll
            for (int k = 0; k < KK; ++k) red[tid][k] += red[tid + sft][k];
        }
        __syncthreads();
    }
    if (tid < KK) out[tid] = fast_tanh(red[0][tid] + br[tid]);
}

extern "C" void kernel_launch(void* const* d_in, const int* in_sizes, int n_in,
                              void* d_out, int out_size, void* d_ws, size_t ws_size,
                              hipStream_t stream) {
    const float* x   = (const float*)d_in[0];
    const float* W1  = (const float*)d_in[1];
    const float* b1  = (const float*)d_in[2];
    const float* W2  = (const float*)d_in[3];
    const float* b2  = (const float*)d_in[4];
    const float* W3  = (const float*)d_in[5];
    const float* b3  = (const float*)d_in[6];
    const float* Wr  = (const float*)d_in[7];
    const float* br  = (const float*)d_in[8];
    const int* labels = (const int*)d_in[9];
    const int* esrc   = (const int*)d_in[10];
    const int* edst   = (const int*)d_in[11];
    const int* elab   = (const int*)d_in[12];
    float* out = (float*)d_out;

    char* ws = (char*)d_ws;
    size_t o = 0;
    auto alloc = [&](size_t bytes) -> void* {
        void* p = ws + o;
        o += (bytes + 255) & ~(size_t)255;
        return p;
    };
    // regionA: recs (14.4 MB) reused for h1/h2 (fp8, 3.2 MB each) after p2
    char* regionA = (char*)alloc((size_t)NBUK * CAP * sizeof(unsigned));
    unsigned* recs = (unsigned*)regionA;
    unsigned char* h1 = (unsigned char*)regionA;
    unsigned char* h2 = (unsigned char*)(regionA + (size_t)NN * FF);

    unsigned* ed1 = (unsigned*)alloc((size_t)NBUK * CAP * sizeof(unsigned));
    unsigned* ed2 = (unsigned*)alloc((size_t)NBUK * CAP * sizeof(unsigned));
    unsigned* ed3 = (unsigned*)alloc((size_t)NBUK * CAP * sizeof(unsigned));
    unsigned* xb = (unsigned*)alloc((size_t)NN * FF);              // fp8 x
    ushort4* Wi  = (ushort4*)alloc((size_t)NWIDX * sizeof(ushort4)); // fp16 interleaved weights
    unsigned char* labels8 = (unsigned char*)alloc(NN);            // u8 labels (hot gather)
    int* cursor = (int*)alloc(NBUK * sizeof(int));
    float* sums = (float*)alloc(LL * FF * sizeof(float));          // adjacent to cursor
    int* gstart = (int*)alloc(NN * sizeof(int));
    int* gcnt   = (int*)alloc(NN * sizeof(int));
    // total ~65 MB of d_ws

    // single memset zeroes cursor + (pad) + sums
    size_t msz = (size_t)((char*)sums - (char*)cursor) + LL * FF * sizeof(float);
    hipMemsetAsync(cursor, 0, msz, stream);

    p1_scatter<<<NBLK_P1, 512, 0, stream>>>(esrc, edst, elab, x, W1, W2, W3, Wi,
                                            labels8, labels, xb, cursor, recs);
    p2_local<<<NBUK, 1024, 0, stream>>>(cursor, recs, labels8, Wi, ed1, ed2, ed3, gstart, gcnt);

    conv_kernel<<<NN / 8, 256, 0, stream>>>((const unsigned char*)xb, h1, gstart, gcnt, ed1, b1, labels);
    conv_kernel<<<NN / 8, 256, 0, stream>>>(h1, h2, gstart, gcnt, ed2, b2, labels);
    conv_kernel<<<NN / 8, 256, 0, stream>>>(h2, h1, gstart, gcnt, ed3, b3, labels);

    lsum_kernel<<<256, 256, 0, stream>>>((const unsigned*)h1, labels, sums);
    resize_kernel<<<1, 256, 0, stream>>>(sums, Wr, br, out);
}

// Round 15
// 274.352 us; speedup vs baseline: 1.0423x; 1.0423x over previous
//
#include <hip/hip_runtime.h>
#include <hip/hip_bf16.h>
#include <hip/hip_fp16.h>
#include <hip/hip_fp8.h>

#define NN 100000        // nodes
#define NE 3200000       // edges
#define FF 32            // node features
#define LL 50            // node labels
#define ELB 10           // edge labels
#define KK 16            // out dim
#define NWIDX (LL * LL * ELB)   // 25000 distinct weight indices

#define CH 8192          // edges per p1 block (long runs -> low write amplification)
#define NBLK_P1 391      // ceil(NE/CH)
#define NBUK 391         // ceil(NN/256) buckets of 256 nodes
#define CAP 9216         // slots per bucket (mean 8192, sigma ~90 -> +11 sigma)
#define LSUM_BLOCKS 256

typedef float floatx2 __attribute__((ext_vector_type(2)));

__device__ __forceinline__ float fast_tanh(float x) {
    float e = __expf(2.0f * x);
    return 1.0f - 2.0f / (e + 1.0f);   // saturates correctly at +/-1
}

// ---------- phase 1: x->fp8 convert + Wi interleave (fp16) + labels8 + LDS counting-sort ----------
// rec u32 = src(17b)<<12 | elab(4b)<<8 | dst_local(8b)
__global__ __launch_bounds__(512) void p1_scatter(const int* __restrict__ esrc,
                                                  const int* __restrict__ edst,
                                                  const int* __restrict__ elab,
                                                  const float* __restrict__ x,
                                                  const float* __restrict__ W1,
                                                  const float* __restrict__ W2,
                                                  const float* __restrict__ W3,
                                                  ushort4* __restrict__ Wi,
                                                  unsigned char* __restrict__ labels8,
                                                  const int* __restrict__ labels,
                                                  unsigned* __restrict__ xb,
                                                  int* __restrict__ cursor,
                                                  unsigned* __restrict__ recs) {
    __shared__ int lcnt[NBUK];        // counts, then per-bucket local cursor
    __shared__ int lofs[NBUK];        // local exclusive prefix (sorted slot base)
    __shared__ int lbase[NBUK];       // global reserved base per bucket
    __shared__ int sc[512];           // scan scratch
    __shared__ unsigned srec[CH];     // 32 KB: records at sorted slots
    __shared__ unsigned sgad[CH];     // 32 KB: global dest index per sorted slot
    int tid = threadIdx.x;
    // x -> fp8 (independent work, folded in to save a launch)
    for (int i = blockIdx.x * 512 + tid; i < NN * FF / 4; i += NBLK_P1 * 512) {
        float4 v = ((const float4*)x)[i];
        __hip_fp8_e4m3 a(v.x), b(v.y), c(v.z), d(v.w);
        xb[i] = (unsigned)a.__x | ((unsigned)b.__x << 8) |
                ((unsigned)c.__x << 16) | ((unsigned)d.__x << 24);
    }
    // interleave W1/W2/W3 -> Wi[widx] = fp16 (w1,w2,w3,0): 200 KB table, one gather serves all 3 convs
    for (int i = blockIdx.x * 512 + tid; i < NWIDX; i += NBLK_P1 * 512) {
        ushort4 w;
        w.x = __half_as_ushort(__float2half(W1[i]));
        w.y = __half_as_ushort(__float2half(W2[i]));
        w.z = __half_as_ushort(__float2half(W3[i]));
        w.w = 0;
        Wi[i] = w;
    }
    // labels -> u8 (100 KB table: 4x fewer lines for p2's hot gather)
    for (int i = blockIdx.x * 512 + tid; i < NN; i += NBLK_P1 * 512)
        labels8[i] = (unsigned char)labels[i];
    for (int i = tid; i < NBUK; i += 512) lcnt[i] = 0;
    __syncthreads();
    long e0 = (long)blockIdx.x * CH;
    long rem = NE - e0;
    int cnt = rem < CH ? (int)rem : CH;   // always divisible by 4
    int nq = cnt >> 2;
    const int4* edst4 = (const int4*)(edst + e0);
    const int4* esrc4 = (const int4*)(esrc + e0);
    const int4* elab4 = (const int4*)(elab + e0);
    // pass A: count per bucket
    for (int i = tid; i < nq; i += 512) {
        int4 d = edst4[i];
        atomicAdd(&lcnt[d.x >> 8], 1);
        atomicAdd(&lcnt[d.y >> 8], 1);
        atomicAdd(&lcnt[d.z >> 8], 1);
        atomicAdd(&lcnt[d.w >> 8], 1);
    }
    __syncthreads();
    // local exclusive prefix over buckets (Hillis-Steele on 512-padded array)
    sc[tid] = (tid < NBUK) ? lcnt[tid] : 0;
    __syncthreads();
    for (int ofs = 1; ofs < 512; ofs <<= 1) {
        int t = (tid >= ofs) ? sc[tid - ofs] : 0;
        __syncthreads();
        sc[tid] += t;
        __syncthreads();
    }
    // pass B: reserve contiguous global runs (cursor is relative, zero-init by memset)
    if (tid < NBUK) {
        int c = lcnt[tid];
        lofs[tid] = sc[tid] - c;     // local sorted base
        lbase[tid] = c ? atomicAdd(&cursor[tid], c) : 0;
        lcnt[tid] = 0;               // reuse as local cursor
    }
    __syncthreads();
    // pass C: re-read edge chunk (L2-hot), stage sorted in LDS
    for (int i = tid; i < nq; i += 512) {
        int4 s4 = esrc4[i];
        int4 l4 = elab4[i];
        int4 d4 = edst4[i];
#pragma unroll
        for (int k = 0; k < 4; ++k) {
            int s  = (&s4.x)[k];
            int d  = (&d4.x)[k];
            int el = (&l4.x)[k];
            int b = d >> 8;
            int pos = atomicAdd(&lcnt[b], 1);
            int slot = lofs[b] + pos;
            srec[slot] = ((unsigned)s << 12) | ((unsigned)el << 8) | (unsigned)(d & 255);
            int rel = lbase[b] + pos;
            sgad[slot] = (rel < CAP) ? (unsigned)(b * CAP + rel) : 0xFFFFFFFFu;
        }
    }
    __syncthreads();
    // pass D: coalesced write-out — consecutive sorted slots -> consecutive global addrs
    for (int i = tid; i < cnt; i += 512) {
        unsigned g = sgad[i];
        if (g != 0xFFFFFFFFu)
            recs[g] = srec[i];
    }
}

// ---------- phase 2: per-bucket exact CSR (permutation in LDS) + coalesced per-layer ed write ----------
// edL u32 = w_fp15(15) | src(17)<<15   (one array per conv layer)
__global__ __launch_bounds__(1024) void p2_local(const int* __restrict__ cursor,
                                                 const unsigned* __restrict__ recs,
                                                 const unsigned char* __restrict__ labels8,
                                                 const ushort4* __restrict__ Wi,
                                                 unsigned* __restrict__ ed1,
                                                 unsigned* __restrict__ ed2,
                                                 unsigned* __restrict__ ed3,
                                                 int* __restrict__ gstart,
                                                 int* __restrict__ gcnt) {
    __shared__ int deg[256], loff[256], lcur[256], sc[256];
    __shared__ int labd[256];
    __shared__ unsigned pk32[CAP];    // 36 KB: widx(15)<<17 | src(17) at sorted slot
    int b = blockIdx.x, tid = threadIdx.x;
    int base = b * CAP;
    int n = cursor[b];
    if (n > CAP) n = CAP;
    if (tid < 256) {
        int node = (b << 8) + tid;
        deg[tid] = 0;
        lcur[tid] = 0;
        labd[tid] = (node < NN) ? (int)labels8[node] : 0;
    }
    __syncthreads();
    for (int i = tid; i < n; i += 1024)
        atomicAdd(&deg[(int)(recs[base + i] & 255)], 1);
    __syncthreads();
    if (tid < 256) sc[tid] = deg[tid];
    __syncthreads();
    for (int ofs = 1; ofs < 256; ofs <<= 1) {
        int t = (tid >= ofs && tid < 256) ? sc[tid - ofs] : 0;
        __syncthreads();
        if (tid < 256) sc[tid] += t;
        __syncthreads();
    }
    if (tid < 256) {
        loff[tid] = sc[tid] - deg[tid];   // exclusive
        int node = (b << 8) + tid;
        if (node < NN) { gstart[node] = base + loff[tid]; gcnt[node] = deg[tid]; }
    }
    __syncthreads();
    // place: resolve widx, stash packed u32 at its CSR slot in LDS (no global scatter)
    for (int i = tid; i < n; i += 1024) {
        unsigned r = recs[base + i];
        int dl  = (int)(r & 255);
        int el  = (int)((r >> 8) & 15);
        int src = (int)(r >> 12);
        int widx = (int)labels8[src] * (LL * ELB) + labd[dl] * ELB + el;
        int ofs = atomicAdd(&lcur[dl], 1);
        pk32[loff[dl] + ofs] = ((unsigned)widx << 17) | (unsigned)src;
    }
    __syncthreads();
    // write-out: sequential slots -> three coalesced u32 streams (no write amplification)
    for (int slot = tid; slot < n; slot += 1024) {
        unsigned v = pk32[slot];
        int widx = (int)(v >> 17);
        unsigned sb = (v & 0x1FFFFu) << 15;   // src in bits 15..31
        ushort4 wv = Wi[widx];                // single 8B gather, 200 KB table
        ed1[base + slot] = (unsigned)(wv.x >> 1) | sb;
        ed2[base + slot] = (unsigned)(wv.y >> 1) | sb;
        ed3[base + slot] = (unsigned)(wv.z >> 1) | sb;
    }
}

// ---------- conv-D (frozen): half-wave per node, LDS-staged broadcast, u32 records,
// ----------       cross-tile ed prefetch + double-buffered stage ----------
__global__ __launch_bounds__(256) void conv_kernel(const unsigned char* __restrict__ xin,
                                                   unsigned char* __restrict__ hout,
                                                   const int* __restrict__ gstart,
                                                   const int* __restrict__ gcnt,
                                                   const unsigned* __restrict__ ed,
                                                   const float* __restrict__ bias,
                                                   const int* __restrict__ labels) {
    __shared__ unsigned stage[2][8][64];   // double-buffered (w_bits, src*32 byte-off)
    int tid = threadIdx.x;
    int hw = tid >> 5, lane = tid & 31;
    int node = (blockIdx.x << 3) + hw;   // grid exact: 12500*8 = 100000
    int s = gstart[node];
    int n = gcnt[node];
    float bb = bias[labels[node]];       // hoisted: latency hides under first tile
    int eg = lane >> 3;          // edge subgroup 0..3
    int fg = (lane & 7) << 2;    // feature byte offset 0..28
    float4 acc = {0.f, 0.f, 0.f, 0.f};
    // prefetch tile 0 (clamped addr stays inside this bucket's region; ws mem is valid)
    unsigned e_cur = ed[s + (lane < n ? lane : 0)];
    int buf = 0;
    for (int base = 0; base < n; base += 32) {
        int idx = base + lane;
        float w = 0.f;
        unsigned so = 0u;
        if (idx < n) {
            // decode u32 rec: w_fp15(15) | src(17)<<15
            unsigned short h = (unsigned short)((e_cur & 0x7FFFu) << 1);
            w = __half2float(__ushort_as_half(h));
            so = (e_cur >> 15) << 5;                // src * 32 bytes (fp8 row)
        }
        ((uint2*)&stage[buf][hw][0])[lane] = make_uint2(__float_as_uint(w), so);
        // issue next tile's ed load BEFORE the j-loop: latency hides under the 8 gathers
        int nb = base + 32;
        if (nb < n) {
            int i2 = nb + lane;
            e_cur = ed[s + (i2 < n ? i2 : nb)];
        }
        __builtin_amdgcn_wave_barrier();   // same-wave DS RAW: DS pipe in-order
#pragma unroll
        for (int j = 0; j < 8; ++j) {
            uint2 ws = ((const uint2*)&stage[buf][hw][0])[j * 4 + eg];
            unsigned pv = *(const unsigned*)(xin + ws.y + fg);   // 4 fp8 feats
            floatx2 lo = __builtin_amdgcn_cvt_pk_f32_fp8((int)pv, false);
            floatx2 hi = __builtin_amdgcn_cvt_pk_f32_fp8((int)pv, true);
            float we = __uint_as_float(ws.x);
            acc.x += we * lo.x;
            acc.y += we * lo.y;
            acc.z += we * hi.x;
            acc.w += we * hi.y;
        }
        buf ^= 1;   // next stage-write targets the other buffer: no trailing barrier
    }
    // reduce across the 4 edge subgroups (lanes differing in bits 3,4)
    acc.x += __shfl_xor(acc.x, 8);  acc.y += __shfl_xor(acc.y, 8);
    acc.z += __shfl_xor(acc.z, 8);  acc.w += __shfl_xor(acc.w, 8);
    acc.x += __shfl_xor(acc.x, 16); acc.y += __shfl_xor(acc.y, 16);
    acc.z += __shfl_xor(acc.z, 16); acc.w += __shfl_xor(acc.w, 16);
    if (lane < 8) {
        __hip_fp8_e4m3 q0(fast_tanh(acc.x + bb));
        __hip_fp8_e4m3 q1(fast_tanh(acc.y + bb));
        __hip_fp8_e4m3 q2(fast_tanh(acc.z + bb));
        __hip_fp8_e4m3 q3(fast_tanh(acc.w + bb));
        unsigned pk = (unsigned)q0.__x | ((unsigned)q1.__x << 8) |
                      ((unsigned)q2.__x << 16) | ((unsigned)q3.__x << 24);
        ((unsigned*)(hout + ((long)node << 5)))[lane] = pk;   // lane==fg/4
    }
}

// ---------- fused label pooling + resize: last block computes the output ----------
__global__ __launch_bounds__(256) void lsum_fused(const unsigned* __restrict__ h,
                                                  const int* __restrict__ labels,
                                                  float* __restrict__ sums,
                                                  const float* __restrict__ Wr,
                                                  const float* __restrict__ br,
                                                  float* __restrict__ out,
                                                  int* __restrict__ donecnt) {
    __shared__ float ls[LL * FF];
    __shared__ int amLast;
    int tid = threadIdx.x;
    for (int i = tid; i < LL * FF; i += 256) ls[i] = 0.f;
    __syncthreads();
    // uint2 loads: 8 feats per iter (halves trips, label loads, index math)
    const uint2* h2 = (const uint2*)h;
    for (int i = blockIdx.x * 256 + tid; i < NN * 4; i += LSUM_BLOCKS * 256) {
        uint2 pv = h2[i];
        int nodei = i >> 2;
        int fb = (i & 3) << 3;
        int l = labels[nodei];
        floatx2 a0 = __builtin_amdgcn_cvt_pk_f32_fp8((int)pv.x, false);
        floatx2 a1 = __builtin_amdgcn_cvt_pk_f32_fp8((int)pv.x, true);
        floatx2 b0 = __builtin_amdgcn_cvt_pk_f32_fp8((int)pv.y, false);
        floatx2 b1 = __builtin_amdgcn_cvt_pk_f32_fp8((int)pv.y, true);
        float* bp = &ls[l * FF + fb];
        atomicAdd(bp + 0, a0.x);
        atomicAdd(bp + 1, a0.y);
        atomicAdd(bp + 2, a1.x);
        atomicAdd(bp + 3, a1.y);
        atomicAdd(bp + 4, b0.x);
        atomicAdd(bp + 5, b0.y);
        atomicAdd(bp + 6, b1.x);
        atomicAdd(bp + 7, b1.y);
    }
    __syncthreads();
    for (int i = tid; i < LL * FF; i += 256) atomicAdd(&sums[i], ls[i]);
    // fence + arrival count; last block performs the resize
    __threadfence();
    if (tid == 0) amLast = (atomicAdd(donecnt, 1) == LSUM_BLOCKS - 1);
    __syncthreads();
    if (!amLast) return;
    __shared__ float red[256][KK];
    float acc[KK];
#pragma unroll
    for (int k = 0; k < KK; ++k) acc[k] = 0.f;
    for (int p = tid; p < LL * FF; p += 256) {
        // atomic read: device-coherent view of sums (per-XCD L2s are not coherent)
        float sv = atomicAdd(&sums[p], 0.0f);
#pragma unroll
        for (int k = 0; k < KK; ++k) acc[k] += sv * Wr[p * KK + k];
    }
#pragma unroll
    for (int k = 0; k < KK; ++k) red[tid][k] = acc[k];
    __syncthreads();
    for (int sft = 128; sft > 0; sft >>= 1) {
        if (tid < sft) {
#pragma unroll
            for (int k = 0; k < KK; ++k) red[tid][k] += red[tid + sft][k];
        }
        __syncthreads();
    }
    if (tid < KK) out[tid] = fast_tanh(red[0][tid] + br[tid]);
}

extern "C" void kernel_launch(void* const* d_in, const int* in_sizes, int n_in,
                              void* d_out, int out_size, void* d_ws, size_t ws_size,
                              hipStream_t stream) {
    const float* x   = (const float*)d_in[0];
    const float* W1  = (const float*)d_in[1];
    const float* b1  = (const float*)d_in[2];
    const float* W2  = (const float*)d_in[3];
    const float* b2  = (const float*)d_in[4];
    const float* W3  = (const float*)d_in[5];
    const float* b3  = (const float*)d_in[6];
    const float* Wr  = (const float*)d_in[7];
    const float* br  = (const float*)d_in[8];
    const int* labels = (const int*)d_in[9];
    const int* esrc   = (const int*)d_in[10];
    const int* edst   = (const int*)d_in[11];
    const int* elab   = (const int*)d_in[12];
    float* out = (float*)d_out;

    char* ws = (char*)d_ws;
    size_t o = 0;
    auto alloc = [&](size_t bytes) -> void* {
        void* p = ws + o;
        o += (bytes + 255) & ~(size_t)255;
        return p;
    };
    // regionA: recs (14.4 MB) reused for h1/h2 (fp8, 3.2 MB each) after p2
    char* regionA = (char*)alloc((size_t)NBUK * CAP * sizeof(unsigned));
    unsigned* recs = (unsigned*)regionA;
    unsigned char* h1 = (unsigned char*)regionA;
    unsigned char* h2 = (unsigned char*)(regionA + (size_t)NN * FF);

    unsigned* ed1 = (unsigned*)alloc((size_t)NBUK * CAP * sizeof(unsigned));
    unsigned* ed2 = (unsigned*)alloc((size_t)NBUK * CAP * sizeof(unsigned));
    unsigned* ed3 = (unsigned*)alloc((size_t)NBUK * CAP * sizeof(unsigned));
    unsigned* xb = (unsigned*)alloc((size_t)NN * FF);              // fp8 x
    ushort4* Wi  = (ushort4*)alloc((size_t)NWIDX * sizeof(ushort4)); // fp16 interleaved weights
    unsigned char* labels8 = (unsigned char*)alloc(NN);            // u8 labels (hot gather)
    int* cursor = (int*)alloc(NBUK * sizeof(int));
    float* sums = (float*)alloc(LL * FF * sizeof(float));          // adjacent to cursor
    int* donecnt = (int*)alloc(sizeof(int));                       // lsum arrival counter
    int* gstart = (int*)alloc(NN * sizeof(int));
    int* gcnt   = (int*)alloc(NN * sizeof(int));
    // total ~65 MB of d_ws

    // single memset zeroes cursor + (pad) + sums + (pad) + donecnt
    size_t msz = (size_t)((char*)donecnt - (char*)cursor) + sizeof(int);
    hipMemsetAsync(cursor, 0, msz, stream);

    p1_scatter<<<NBLK_P1, 512, 0, stream>>>(esrc, edst, elab, x, W1, W2, W3, Wi,
                                            labels8, labels, xb, cursor, recs);
    p2_local<<<NBUK, 1024, 0, stream>>>(cursor, recs, labels8, Wi, ed1, ed2, ed3, gstart, gcnt);

    conv_kernel<<<NN / 8, 256, 0, stream>>>((const unsigned char*)xb, h1, gstart, gcnt, ed1, b1, labels);
    conv_kernel<<<NN / 8, 256, 0, stream>>>(h1, h2, gstart, gcnt, ed2, b2, labels);
    conv_kernel<<<NN / 8, 256, 0, stream>>>(h2, h1, gstart, gcnt, ed3, b3, labels);

    lsum_fused<<<LSUM_BLOCKS, 256, 0, stream>>>((const unsigned*)h1, labels, sums,
                                                Wr, br, out, donecnt);
}

// Round 16
// 257.496 us; speedup vs baseline: 1.1105x; 1.0655x over previous
//
#include <hip/hip_runtime.h>
#include <hip/hip_bf16.h>
#include <hip/hip_fp16.h>
#include <hip/hip_fp8.h>

#define NN 100000        // nodes
#define NE 3200000       // edges
#define FF 32            // node features
#define LL 50            // node labels
#define ELB 10           // edge labels
#define KK 16            // out dim
#define NWIDX (LL * LL * ELB)   // 25000 distinct weight indices

#define CH 8192          // edges per p1 block (long runs -> low write amplification)
#define NBLK_P1 391      // ceil(NE/CH)
#define NBUK 391         // ceil(NN/256) buckets of 256 nodes
#define CAP 9216         // slots per bucket (mean 8192, sigma ~90 -> +11 sigma)

typedef float floatx2 __attribute__((ext_vector_type(2)));

__device__ __forceinline__ float fast_tanh(float x) {
    float e = __expf(2.0f * x);
    return 1.0f - 2.0f / (e + 1.0f);   // saturates correctly at +/-1
}

// ---------- phase 1: x->fp8 convert + Wi interleave (fp16) + labels8 + LDS counting-sort ----------
// rec u32 = src(17b)<<12 | elab(4b)<<8 | dst_local(8b)
__global__ __launch_bounds__(512) void p1_scatter(const int* __restrict__ esrc,
                                                  const int* __restrict__ edst,
                                                  const int* __restrict__ elab,
                                                  const float* __restrict__ x,
                                                  const float* __restrict__ W1,
                                                  const float* __restrict__ W2,
                                                  const float* __restrict__ W3,
                                                  ushort4* __restrict__ Wi,
                                                  unsigned char* __restrict__ labels8,
                                                  const int* __restrict__ labels,
                                                  unsigned* __restrict__ xb,
                                                  int* __restrict__ cursor,
                                                  unsigned* __restrict__ recs) {
    __shared__ int lcnt[NBUK];        // counts, then per-bucket local cursor
    __shared__ int lofs[NBUK];        // local exclusive prefix (sorted slot base)
    __shared__ int lbase[NBUK];       // global reserved base per bucket
    __shared__ int sc[512];           // scan scratch
    __shared__ unsigned srec[CH];     // 32 KB: records at sorted slots
    __shared__ unsigned sgad[CH];     // 32 KB: global dest index per sorted slot
    int tid = threadIdx.x;
    // x -> fp8 (independent work, folded in to save a launch)
    for (int i = blockIdx.x * 512 + tid; i < NN * FF / 4; i += NBLK_P1 * 512) {
        float4 v = ((const float4*)x)[i];
        __hip_fp8_e4m3 a(v.x), b(v.y), c(v.z), d(v.w);
        xb[i] = (unsigned)a.__x | ((unsigned)b.__x << 8) |
                ((unsigned)c.__x << 16) | ((unsigned)d.__x << 24);
    }
    // interleave W1/W2/W3 -> Wi[widx] = fp16 (w1,w2,w3,0): 200 KB table, one gather serves all 3 convs
    for (int i = blockIdx.x * 512 + tid; i < NWIDX; i += NBLK_P1 * 512) {
        ushort4 w;
        w.x = __half_as_ushort(__float2half(W1[i]));
        w.y = __half_as_ushort(__float2half(W2[i]));
        w.z = __half_as_ushort(__float2half(W3[i]));
        w.w = 0;
        Wi[i] = w;
    }
    // labels -> u8 (100 KB table: 4x fewer lines for p2's hot gather)
    for (int i = blockIdx.x * 512 + tid; i < NN; i += NBLK_P1 * 512)
        labels8[i] = (unsigned char)labels[i];
    for (int i = tid; i < NBUK; i += 512) lcnt[i] = 0;
    __syncthreads();
    long e0 = (long)blockIdx.x * CH;
    long rem = NE - e0;
    int cnt = rem < CH ? (int)rem : CH;   // always divisible by 4
    int nq = cnt >> 2;
    const int4* edst4 = (const int4*)(edst + e0);
    const int4* esrc4 = (const int4*)(esrc + e0);
    const int4* elab4 = (const int4*)(elab + e0);
    // pass A: count per bucket
    for (int i = tid; i < nq; i += 512) {
        int4 d = edst4[i];
        atomicAdd(&lcnt[d.x >> 8], 1);
        atomicAdd(&lcnt[d.y >> 8], 1);
        atomicAdd(&lcnt[d.z >> 8], 1);
        atomicAdd(&lcnt[d.w >> 8], 1);
    }
    __syncthreads();
    // local exclusive prefix over buckets (Hillis-Steele on 512-padded array)
    sc[tid] = (tid < NBUK) ? lcnt[tid] : 0;
    __syncthreads();
    for (int ofs = 1; ofs < 512; ofs <<= 1) {
        int t = (tid >= ofs) ? sc[tid - ofs] : 0;
        __syncthreads();
        sc[tid] += t;
        __syncthreads();
    }
    // pass B: reserve contiguous global runs (cursor is relative, zero-init by memset)
    if (tid < NBUK) {
        int c = lcnt[tid];
        lofs[tid] = sc[tid] - c;     // local sorted base
        lbase[tid] = c ? atomicAdd(&cursor[tid], c) : 0;
        lcnt[tid] = 0;               // reuse as local cursor
    }
    __syncthreads();
    // pass C: re-read edge chunk (L2-hot), stage sorted in LDS
    for (int i = tid; i < nq; i += 512) {
        int4 s4 = esrc4[i];
        int4 l4 = elab4[i];
        int4 d4 = edst4[i];
#pragma unroll
        for (int k = 0; k < 4; ++k) {
            int s  = (&s4.x)[k];
            int d  = (&d4.x)[k];
            int el = (&l4.x)[k];
            int b = d >> 8;
            int pos = atomicAdd(&lcnt[b], 1);
            int slot = lofs[b] + pos;
            srec[slot] = ((unsigned)s << 12) | ((unsigned)el << 8) | (unsigned)(d & 255);
            int rel = lbase[b] + pos;
            sgad[slot] = (rel < CAP) ? (unsigned)(b * CAP + rel) : 0xFFFFFFFFu;
        }
    }
    __syncthreads();
    // pass D: coalesced write-out — consecutive sorted slots -> consecutive global addrs
    for (int i = tid; i < cnt; i += 512) {
        unsigned g = sgad[i];
        if (g != 0xFFFFFFFFu)
            recs[g] = srec[i];
    }
}

// ---------- phase 2: per-bucket exact CSR (permutation in LDS) + coalesced per-layer ed write ----------
// edL u32 = w_fp15(15) | src(17)<<15   (one array per conv layer)
__global__ __launch_bounds__(1024) void p2_local(const int* __restrict__ cursor,
                                                 const unsigned* __restrict__ recs,
                                                 const unsigned char* __restrict__ labels8,
                                                 const ushort4* __restrict__ Wi,
                                                 unsigned* __restrict__ ed1,
                                                 unsigned* __restrict__ ed2,
                                                 unsigned* __restrict__ ed3,
                                                 int* __restrict__ gstart,
                                                 int* __restrict__ gcnt) {
    __shared__ int deg[256], loff[256], lcur[256], sc[256];
    __shared__ int labd[256];
    __shared__ unsigned pk32[CAP];    // 36 KB: widx(15)<<17 | src(17) at sorted slot
    int b = blockIdx.x, tid = threadIdx.x;
    int base = b * CAP;
    int n = cursor[b];
    if (n > CAP) n = CAP;
    if (tid < 256) {
        int node = (b << 8) + tid;
        deg[tid] = 0;
        lcur[tid] = 0;
        labd[tid] = (node < NN) ? (int)labels8[node] : 0;
    }
    __syncthreads();
    for (int i = tid; i < n; i += 1024)
        atomicAdd(&deg[(int)(recs[base + i] & 255)], 1);
    __syncthreads();
    if (tid < 256) sc[tid] = deg[tid];
    __syncthreads();
    for (int ofs = 1; ofs < 256; ofs <<= 1) {
        int t = (tid >= ofs && tid < 256) ? sc[tid - ofs] : 0;
        __syncthreads();
        if (tid < 256) sc[tid] += t;
        __syncthreads();
    }
    if (tid < 256) {
        loff[tid] = sc[tid] - deg[tid];   // exclusive
        int node = (b << 8) + tid;
        if (node < NN) { gstart[node] = base + loff[tid]; gcnt[node] = deg[tid]; }
    }
    __syncthreads();
    // place: resolve widx, stash packed u32 at its CSR slot in LDS (no global scatter)
    for (int i = tid; i < n; i += 1024) {
        unsigned r = recs[base + i];
        int dl  = (int)(r & 255);
        int el  = (int)((r >> 8) & 15);
        int src = (int)(r >> 12);
        int widx = (int)labels8[src] * (LL * ELB) + labd[dl] * ELB + el;
        int ofs = atomicAdd(&lcur[dl], 1);
        pk32[loff[dl] + ofs] = ((unsigned)widx << 17) | (unsigned)src;
    }
    __syncthreads();
    // write-out: sequential slots -> three coalesced u32 streams (no write amplification)
    for (int slot = tid; slot < n; slot += 1024) {
        unsigned v = pk32[slot];
        int widx = (int)(v >> 17);
        unsigned sb = (v & 0x1FFFFu) << 15;   // src in bits 15..31
        ushort4 wv = Wi[widx];                // single 8B gather, 200 KB table
        ed1[base + slot] = (unsigned)(wv.x >> 1) | sb;
        ed2[base + slot] = (unsigned)(wv.y >> 1) | sb;
        ed3[base + slot] = (unsigned)(wv.z >> 1) | sb;
    }
}

// ---------- conv-D (frozen): half-wave per node, LDS-staged broadcast, u32 records,
// ----------       cross-tile ed prefetch + double-buffered stage ----------
__global__ __launch_bounds__(256) void conv_kernel(const unsigned char* __restrict__ xin,
                                                   unsigned char* __restrict__ hout,
                                                   const int* __restrict__ gstart,
                                                   const int* __restrict__ gcnt,
                                                   const unsigned* __restrict__ ed,
                                                   const float* __restrict__ bias,
                                                   const int* __restrict__ labels) {
    __shared__ unsigned stage[2][8][64];   // double-buffered (w_bits, src*32 byte-off)
    int tid = threadIdx.x;
    int hw = tid >> 5, lane = tid & 31;
    int node = (blockIdx.x << 3) + hw;   // grid exact: 12500*8 = 100000
    int s = gstart[node];
    int n = gcnt[node];
    float bb = bias[labels[node]];       // hoisted: latency hides under first tile
    int eg = lane >> 3;          // edge subgroup 0..3
    int fg = (lane & 7) << 2;    // feature byte offset 0..28
    float4 acc = {0.f, 0.f, 0.f, 0.f};
    // prefetch tile 0 (clamped addr stays inside this bucket's region; ws mem is valid)
    unsigned e_cur = ed[s + (lane < n ? lane : 0)];
    int buf = 0;
    for (int base = 0; base < n; base += 32) {
        int idx = base + lane;
        float w = 0.f;
        unsigned so = 0u;
        if (idx < n) {
            // decode u32 rec: w_fp15(15) | src(17)<<15
            unsigned short h = (unsigned short)((e_cur & 0x7FFFu) << 1);
            w = __half2float(__ushort_as_half(h));
            so = (e_cur >> 15) << 5;                // src * 32 bytes (fp8 row)
        }
        ((uint2*)&stage[buf][hw][0])[lane] = make_uint2(__float_as_uint(w), so);
        // issue next tile's ed load BEFORE the j-loop: latency hides under the 8 gathers
        int nb = base + 32;
        if (nb < n) {
            int i2 = nb + lane;
            e_cur = ed[s + (i2 < n ? i2 : nb)];
        }
        __builtin_amdgcn_wave_barrier();   // same-wave DS RAW: DS pipe in-order
#pragma unroll
        for (int j = 0; j < 8; ++j) {
            uint2 ws = ((const uint2*)&stage[buf][hw][0])[j * 4 + eg];
            unsigned pv = *(const unsigned*)(xin + ws.y + fg);   // 4 fp8 feats
            floatx2 lo = __builtin_amdgcn_cvt_pk_f32_fp8((int)pv, false);
            floatx2 hi = __builtin_amdgcn_cvt_pk_f32_fp8((int)pv, true);
            float we = __uint_as_float(ws.x);
            acc.x += we * lo.x;
            acc.y += we * lo.y;
            acc.z += we * hi.x;
            acc.w += we * hi.y;
        }
        buf ^= 1;   // next stage-write targets the other buffer: no trailing barrier
    }
    // reduce across the 4 edge subgroups (lanes differing in bits 3,4)
    acc.x += __shfl_xor(acc.x, 8);  acc.y += __shfl_xor(acc.y, 8);
    acc.z += __shfl_xor(acc.z, 8);  acc.w += __shfl_xor(acc.w, 8);
    acc.x += __shfl_xor(acc.x, 16); acc.y += __shfl_xor(acc.y, 16);
    acc.z += __shfl_xor(acc.z, 16); acc.w += __shfl_xor(acc.w, 16);
    if (lane < 8) {
        __hip_fp8_e4m3 q0(fast_tanh(acc.x + bb));
        __hip_fp8_e4m3 q1(fast_tanh(acc.y + bb));
        __hip_fp8_e4m3 q2(fast_tanh(acc.z + bb));
        __hip_fp8_e4m3 q3(fast_tanh(acc.w + bb));
        unsigned pk = (unsigned)q0.__x | ((unsigned)q1.__x << 8) |
                      ((unsigned)q2.__x << 16) | ((unsigned)q3.__x << 24);
        ((unsigned*)(hout + ((long)node << 5)))[lane] = pk;   // lane==fg/4
    }
}

// ---------- label pooling: sums[L][F] from fp8 h ----------
// 512 threads/block (8 waves/CU): kernel is latency-bound at 4 waves/CU (42us, 0.5% VALU)
__global__ __launch_bounds__(512) void lsum_kernel(const unsigned* __restrict__ h,
                                                   const int* __restrict__ labels,
                                                   float* __restrict__ sums) {
    __shared__ float ls[LL * FF];
    int tid = threadIdx.x;
    for (int i = tid; i < LL * FF; i += 512) ls[i] = 0.f;
    __syncthreads();
    for (int i = blockIdx.x * 512 + tid; i < NN * 8; i += 256 * 512) {
        unsigned pv = h[i];
        int nodei = i >> 3;
        int fb = (i & 7) << 2;
        int l = labels[nodei];
        floatx2 lo = __builtin_amdgcn_cvt_pk_f32_fp8((int)pv, false);
        floatx2 hi = __builtin_amdgcn_cvt_pk_f32_fp8((int)pv, true);
        float* bp = &ls[l * FF + fb];
        atomicAdd(bp + 0, lo.x);
        atomicAdd(bp + 1, lo.y);
        atomicAdd(bp + 2, hi.x);
        atomicAdd(bp + 3, hi.y);
    }
    __syncthreads();
    for (int i = tid; i < LL * FF; i += 512) atomicAdd(&sums[i], ls[i]);
}

// ---------- final resize ----------
__global__ __launch_bounds__(256) void resize_kernel(const float* __restrict__ sums,
                                                     const float* __restrict__ Wr,
                                                     const float* __restrict__ br,
                                                     float* __restrict__ out) {
    __shared__ float red[256][KK];
    int tid = threadIdx.x;
    float acc[KK];
#pragma unroll
    for (int k = 0; k < KK; ++k) acc[k] = 0.f;
    for (int p = tid; p < LL * FF; p += 256) {
        float sv = sums[p];
#pragma unroll
        for (int k = 0; k < KK; ++k) acc[k] += sv * Wr[p * KK + k];
    }
#pragma unroll
    for (int k = 0; k < KK; ++k) red[tid][k] = acc[k];
    __syncthreads();
    for (int sft = 128; sft > 0; sft >>= 1) {
        if (tid < sft) {
#pragma unroll
            for (int k = 0; k < KK; ++k) red[tid][k] += red[tid + sft][k];
        }
        __syncthreads();
    }
    if (tid < KK) out[tid] = fast_tanh(red[0][tid] + br[tid]);
}

extern "C" void kernel_launch(void* const* d_in, const int* in_sizes, int n_in,
                              void* d_out, int out_size, void* d_ws, size_t ws_size,
                              hipStream_t stream) {
    const float* x   = (const float*)d_in[0];
    const float* W1  = (const float*)d_in[1];
    const float* b1  = (const float*)d_in[2];
    const float* W2  = (const float*)d_in[3];
    const float* b2  = (const float*)d_in[4];
    const float* W3  = (const float*)d_in[5];
    const float* b3  = (const float*)d_in[6];
    const float* Wr  = (const float*)d_in[7];
    const float* br  = (const float*)d_in[8];
    const int* labels = (const int*)d_in[9];
    const int* esrc   = (const int*)d_in[10];
    const int* edst   = (const int*)d_in[11];
    const int* elab   = (const int*)d_in[12];
    float* out = (float*)d_out;

    char* ws = (char*)d_ws;
    size_t o = 0;
    auto alloc = [&](size_t bytes) -> void* {
        void* p = ws + o;
        o += (bytes + 255) & ~(size_t)255;
        return p;
    };
    // regionA: recs (14.4 MB) reused for h1/h2 (fp8, 3.2 MB each) after p2
    char* regionA = (char*)alloc((size_t)NBUK * CAP * sizeof(unsigned));
    unsigned* recs = (unsigned*)regionA;
    unsigned char* h1 = (unsigned char*)regionA;
    unsigned char* h2 = (unsigned char*)(regionA + (size_t)NN * FF);

    unsigned* ed1 = (unsigned*)alloc((size_t)NBUK * CAP * sizeof(unsigned));
    unsigned* ed2 = (unsigned*)alloc((size_t)NBUK * CAP * sizeof(unsigned));
    unsigned* ed3 = (unsigned*)alloc((size_t)NBUK * CAP * sizeof(unsigned));
    unsigned* xb = (unsigned*)alloc((size_t)NN * FF);              // fp8 x
    ushort4* Wi  = (ushort4*)alloc((size_t)NWIDX * sizeof(ushort4)); // fp16 interleaved weights
    unsigned char* labels8 = (unsigned char*)alloc(NN);            // u8 labels (hot gather)
    int* cursor = (int*)alloc(NBUK * sizeof(int));
    float* sums = (float*)alloc(LL * FF * sizeof(float));          // adjacent to cursor
    int* gstart = (int*)alloc(NN * sizeof(int));
    int* gcnt   = (int*)alloc(NN * sizeof(int));
    // total ~65 MB of d_ws

    // single memset zeroes cursor + (pad) + sums
    size_t msz = (size_t)((char*)sums - (char*)cursor) + LL * FF * sizeof(float);
    hipMemsetAsync(cursor, 0, msz, stream);

    p1_scatter<<<NBLK_P1, 512, 0, stream>>>(esrc, edst, elab, x, W1, W2, W3, Wi,
                                            labels8, labels, xb, cursor, recs);
    p2_local<<<NBUK, 1024, 0, stream>>>(cursor, recs, labels8, Wi, ed1, ed2, ed3, gstart, gcnt);

    conv_kernel<<<NN / 8, 256, 0, stream>>>((const unsigned char*)xb, h1, gstart, gcnt, ed1, b1, labels);
    conv_kernel<<<NN / 8, 256, 0, stream>>>(h1, h2, gstart, gcnt, ed2, b2, labels);
    conv_kernel<<<NN / 8, 256, 0, stream>>>(h2, h1, gstart, gcnt, ed3, b3, labels);

    lsum_kernel<<<256, 512, 0, stream>>>((const unsigned*)h1, labels, sums);
    resize_kernel<<<1, 256, 0, stream>>>(sums, Wr, br, out);
}